// Round 9
// baseline (299.681 us; speedup 1.0000x reference)
//
#include <hip/hip_runtime.h>
#include <math.h>

// B=1, L=256, DP=128, DB=128, H=8, DH=32, H*DH=256
// bf16 MFMA 16x16x32. Q/K use a 4-row-tiled layout X4[(p>>2)][n][p&3];
// V projection stores D-fragments directly into Vtb. NO atomics anywhere.
// R11: K-scale folded into Wk; fast sigmoid; k_av LDS-transposed stores.
// R12: proj dbuf A-frags; stage-1 merged into k_pre.
// R14: k_pre structural ILP (LDS Wb, sched_barrier pin, 2 rows/thread).
// R15: gate fused into k_av (G2 dead); logits z=8; wave-per-row softmax.
// R16: k_av nt4 split across blocks; Ts halved -> 44us.
// R17 REGRESSED: dropping As staging exposed L2 latency on MFMA A-chain.
// R18: k_av 8-wave blocks sharing one As (70.7KB, 2 blk/CU, 16 waves/CU)
//      -- kept. k_proj MERGE REGRESSED: co-compiled branches inflated
//      VGPR 88->140, occupancy 10%, 62us (rule: don't co-compile two
//      full MFMA pipelines into one kernel).
// R19: split projections back into separate k_proj_qkg (128,4,2) and
//      k_projv (256,4) -- per-kernel regalloc restored. k_av 8-wave kept.
//      Pure repartitioning revert -> bit-identical values.
//
// Fragment layouts (HW-verified):
//   A-frag: lane holds A[m=lane&15][k=(lane>>4)*8+j], j=0..7 (16B)
//   B-frag: lane holds B[k=(lane>>4)*8+j][n=lane&15]
//   D:      lane holds D[row=(lane>>4)*4+reg][col=lane&15]
//
// Workspace (byte offsets):
//   PNb  u16 [65536][128]     @ 0            16,777,216   LN(pair), row p=r*256+sc
//   Qr4  u16 tiled [16384][256][4] @ 16777216 33,554,432  (p>>2, n, p&3), p=(i,sc)
//   Kr4  u16 tiled             @ 50331648    33,554,432
//   Vtb  u16 [8][8192][256]   @ 83886080     33,554,432   [h][k*32+d][j]
//   GOb  u16 [65536][256]     @ 150994944    33,554,432   row = i*256+k
//   Bp   f32 [8][256][256]    @ 184549376     2,097,152
//   Ab   u16 [8][256][256]    @ 186646528     1,048,576
//   Wtb  u16 [4][256][128]    @ 187695104       262,144   W{q,k,v,g}^T [n][k]
//   Wotb u16 [128][256]       @ 187957248        65,536   Wo^T [c][e]
//   Lg2  f32 [8][8][256][256] @ 188022784    16,777,216   split-K logit slices

typedef unsigned short u16;
typedef __attribute__((ext_vector_type(8))) short short8;
typedef __attribute__((ext_vector_type(4))) short short4v;
typedef __attribute__((ext_vector_type(4))) float float4v;

__device__ __forceinline__ u16 f2bf(float f) {
  unsigned int u = __float_as_uint(f);
  u += 0x7FFFu + ((u >> 16) & 1u);
  return (u16)(u >> 16);
}
__device__ __forceinline__ float bf2f(u16 h) {
  return __uint_as_float(((unsigned int)h) << 16);
}

// ---------------- K_pre (R14): grid-union of ln / lnbias+bproj / wcvt -------
__global__ __launch_bounds__(256, 4) void k_pre(
    const float* __restrict__ x1, const float* __restrict__ g1,
    const float* __restrict__ b1, u16* __restrict__ y1,
    const float* __restrict__ x2, const float* __restrict__ g2,
    const float* __restrict__ b2, const float* __restrict__ Wb,
    float* __restrict__ Bp,
    const float* __restrict__ Wq, const float* __restrict__ Wk,
    const float* __restrict__ Wv, const float* __restrict__ Wg,
    const float* __restrict__ Wo, u16* __restrict__ Wtb, u16* __restrict__ Wotb) {
  __shared__ float wbs[128 * 9];  // lnbias branch only: Wb staged, pitch 9
  const int bid = blockIdx.x;
  const int t = threadIdx.x;
  if (bid < 1024) {
    // ---- LayerNorm(pair) -> PNb, 2 independent rows per thread ----
    const int row = t >> 3, h = t & 7;
    const int p0 = bid * 64 + row;
    const int p1 = p0 + 32;
    const float* rpA = x1 + (size_t)p0 * 128 + h * 16;
    const float* rpB = x1 + (size_t)p1 * 128 + h * 16;
    float4 xa[4], xb[4], gv4[4], bv4[4];
#pragma unroll
    for (int i = 0; i < 4; ++i) xa[i] = ((const float4*)rpA)[i];
#pragma unroll
    for (int i = 0; i < 4; ++i) xb[i] = ((const float4*)rpB)[i];
#pragma unroll
    for (int i = 0; i < 4; ++i) {
      gv4[i] = ((const float4*)(g1 + h * 16))[i];
      bv4[i] = ((const float4*)(b1 + h * 16))[i];
    }
    __builtin_amdgcn_sched_barrier(0);  // pin: all 16 loads issued above
    float sA = 0.f, ssA = 0.f, sB = 0.f, ssB = 0.f;
#pragma unroll
    for (int i = 0; i < 4; ++i) {
      sA += (xa[i].x + xa[i].y) + (xa[i].z + xa[i].w);
      ssA += (xa[i].x * xa[i].x + xa[i].y * xa[i].y) + (xa[i].z * xa[i].z + xa[i].w * xa[i].w);
      sB += (xb[i].x + xb[i].y) + (xb[i].z + xb[i].w);
      ssB += (xb[i].x * xb[i].x + xb[i].y * xb[i].y) + (xb[i].z * xb[i].z + xb[i].w * xb[i].w);
    }
#pragma unroll
    for (int off = 1; off <= 4; off <<= 1) {
      sA += __shfl_xor(sA, off);
      ssA += __shfl_xor(ssA, off);
      sB += __shfl_xor(sB, off);
      ssB += __shfl_xor(ssB, off);
    }
    float mA = sA * (1.0f / 128.0f);
    float invA = rsqrtf(ssA * (1.0f / 128.0f) - mA * mA + 1e-5f);
    float mB = sB * (1.0f / 128.0f);
    float invB = rsqrtf(ssB * (1.0f / 128.0f) - mB * mB + 1e-5f);
    short8 oA[2], oB[2];
#pragma unroll
    for (int i4 = 0; i4 < 4; ++i4) {
      float4 gv = gv4[i4], bv = bv4[i4];
      oA[i4 >> 1][(i4 & 1) * 4 + 0] = (short)f2bf((xa[i4].x - mA) * invA * gv.x + bv.x);
      oA[i4 >> 1][(i4 & 1) * 4 + 1] = (short)f2bf((xa[i4].y - mA) * invA * gv.y + bv.y);
      oA[i4 >> 1][(i4 & 1) * 4 + 2] = (short)f2bf((xa[i4].z - mA) * invA * gv.z + bv.z);
      oA[i4 >> 1][(i4 & 1) * 4 + 3] = (short)f2bf((xa[i4].w - mA) * invA * gv.w + bv.w);
      oB[i4 >> 1][(i4 & 1) * 4 + 0] = (short)f2bf((xb[i4].x - mB) * invB * gv.x + bv.x);
      oB[i4 >> 1][(i4 & 1) * 4 + 1] = (short)f2bf((xb[i4].y - mB) * invB * gv.y + bv.y);
      oB[i4 >> 1][(i4 & 1) * 4 + 2] = (short)f2bf((xb[i4].z - mB) * invB * gv.z + bv.z);
      oB[i4 >> 1][(i4 & 1) * 4 + 3] = (short)f2bf((xb[i4].w - mB) * invB * gv.w + bv.w);
    }
    u16* opA = y1 + (size_t)p0 * 128 + h * 16;
    *(short8*)opA = oA[0];
    *(short8*)(opA + 8) = oA[1];
    u16* opB = y1 + (size_t)p1 * 128 + h * 16;
    *(short8*)opB = oB[0];
    *(short8*)(opB + 8) = oB[1];
  } else if (bid < 2048) {
    // ---- LN(bias) + Wb proj -> Bp, 2 rows/thread, Wb from LDS ----
    {
      float4 wv = ((const float4*)Wb)[t];
      const int k = t >> 1, e0 = (t & 1) * 4;
      wbs[k * 9 + e0 + 0] = wv.x;
      wbs[k * 9 + e0 + 1] = wv.y;
      wbs[k * 9 + e0 + 2] = wv.z;
      wbs[k * 9 + e0 + 3] = wv.w;
    }
    const int row = t >> 3, h = t & 7;
    const int p0 = (bid - 1024) * 64 + row;
    const int p1 = p0 + 32;
    const int r0 = p0 >> 8, sc0 = p0 & 255;
    const int r1 = p1 >> 8, sc1 = p1 & 255;
    const float* rpA = x2 + (size_t)p0 * 128 + h * 16;
    const float* rpB = x2 + (size_t)p1 * 128 + h * 16;
    float4 xa[4], xb[4], gv4[4], bv4[4];
#pragma unroll
    for (int i = 0; i < 4; ++i) xa[i] = ((const float4*)rpA)[i];
#pragma unroll
    for (int i = 0; i < 4; ++i) xb[i] = ((const float4*)rpB)[i];
#pragma unroll
    for (int i = 0; i < 4; ++i) {
      gv4[i] = ((const float4*)(g2 + h * 16))[i];
      bv4[i] = ((const float4*)(b2 + h * 16))[i];
    }
    __builtin_amdgcn_sched_barrier(0);
    __syncthreads();  // wbs ready
    float sA = 0.f, ssA = 0.f, sB = 0.f, ssB = 0.f;
#pragma unroll
    for (int i = 0; i < 4; ++i) {
      sA += (xa[i].x + xa[i].y) + (xa[i].z + xa[i].w);
      ssA += (xa[i].x * xa[i].x + xa[i].y * xa[i].y) + (xa[i].z * xa[i].z + xa[i].w * xa[i].w);
      sB += (xb[i].x + xb[i].y) + (xb[i].z + xb[i].w);
      ssB += (xb[i].x * xb[i].x + xb[i].y * xb[i].y) + (xb[i].z * xb[i].z + xb[i].w * xb[i].w);
    }
#pragma unroll
    for (int off = 1; off <= 4; off <<= 1) {
      sA += __shfl_xor(sA, off);
      ssA += __shfl_xor(ssA, off);
      sB += __shfl_xor(sB, off);
      ssB += __shfl_xor(ssB, off);
    }
    float mA = sA * (1.0f / 128.0f);
    float invA = rsqrtf(ssA * (1.0f / 128.0f) - mA * mA + 1e-5f);
    float mB = sB * (1.0f / 128.0f);
    float invB = rsqrtf(ssB * (1.0f / 128.0f) - mB * mB + 1e-5f);
    float pa[8], pb[8];
#pragma unroll
    for (int e = 0; e < 8; ++e) {
      pa[e] = 0.f;
      pb[e] = 0.f;
    }
#pragma unroll
    for (int i4 = 0; i4 < 4; ++i4) {
      float4 gv = gv4[i4], bv = bv4[i4];
      float xsA[4] = {xa[i4].x, xa[i4].y, xa[i4].z, xa[i4].w};
      float xsB[4] = {xb[i4].x, xb[i4].y, xb[i4].z, xb[i4].w};
      float gs[4] = {gv.x, gv.y, gv.z, gv.w};
      float bs[4] = {bv.x, bv.y, bv.z, bv.w};
#pragma unroll
      for (int q = 0; q < 4; ++q) {
        const int k = h * 16 + i4 * 4 + q;
        float xnA = (xsA[q] - mA) * invA * gs[q] + bs[q];
        float xnB = (xsB[q] - mB) * invB * gs[q] + bs[q];
        const float* wr = &wbs[k * 9];
#pragma unroll
        for (int e = 0; e < 8; ++e) {
          float w = wr[e];
          pa[e] += xnA * w;
          pb[e] += xnB * w;
        }
      }
    }
#pragma unroll
    for (int off = 1; off <= 4; off <<= 1) {
#pragma unroll
      for (int e = 0; e < 8; ++e) {
        pa[e] += __shfl_xor(pa[e], off);
        pb[e] += __shfl_xor(pb[e], off);
      }
    }
    float vA = (h == 0) ? pa[0]
             : (h == 1) ? pa[1]
             : (h == 2) ? pa[2]
             : (h == 3) ? pa[3]
             : (h == 4) ? pa[4]
             : (h == 5) ? pa[5]
             : (h == 6) ? pa[6]
                        : pa[7];
    float vB = (h == 0) ? pb[0]
             : (h == 1) ? pb[1]
             : (h == 2) ? pb[2]
             : (h == 3) ? pb[3]
             : (h == 4) ? pb[4]
             : (h == 5) ? pb[5]
             : (h == 6) ? pb[6]
                        : pb[7];
    Bp[(size_t)h * 65536 + (size_t)sc0 * 256 + r0] = vA;
    Bp[(size_t)h * 65536 + (size_t)sc1 * 256 + r1] = vB;
  } else {
    // ---- weight convert/transpose: coalesced loads, scattered stores ----
    int idx = (bid - 2048) * 256 + t;
    if (idx < 131072) {
      int w = idx >> 15, r = idx & 32767;
      int k = r >> 8, n = r & 255;
      const float* W = (w == 0) ? Wq : (w == 1) ? Wk : (w == 2) ? Wv : Wg;
      const float sW = (w == 1) ? 0.0625f : 1.0f;
      Wtb[(size_t)w * 32768 + n * 128 + k] = f2bf(W[k * 256 + n] * sW);
    } else {
      int r = idx - 131072;
      int e = r >> 7, c = r & 127;
      Wotb[c * 256 + e] = f2bf(Wo[e * 128 + c]);
    }
  }
}

// ---------------- K4 (R19 = R16): Q/K projections, separate kernel ----------
// grid (128 stripes of 512 rows, 4 col-quarters, 2 weights). Dbuf A-frags.
__global__ __launch_bounds__(256) void k_proj_qkg(const u16* __restrict__ PNb,
                                                  const u16* __restrict__ Wtb,
                                                  u16* __restrict__ Qr4,
                                                  u16* __restrict__ Kr4) {
  const int t = threadIdx.x;
  const int wid = t >> 6, lane = t & 63;
  const int mrow = lane & 15, quad = lane >> 4;
  const int stripe = blockIdx.x;
  const int n0 = blockIdx.y * 64;
  const int wsel = blockIdx.z;  // 0:Q 1:K
  const u16* Wt = Wtb + (size_t)wsel * 32768;
  u16* dst = (wsel == 0) ? Qr4 : Kr4;

  short8 bfr[4][4];
#pragma unroll
  for (int nt = 0; nt < 4; ++nt)
#pragma unroll
    for (int kk = 0; kk < 4; ++kk)
      bfr[nt][kk] = *(const short8*)(Wt + (size_t)(n0 + nt * 16 + mrow) * 128 + kk * 32 + quad * 8);

  short8 afr[2][4], afrn[2][4];
  {
    const int pw = stripe * 512 + wid * 32;
#pragma unroll
    for (int mt = 0; mt < 2; ++mt)
#pragma unroll
      for (int kk = 0; kk < 4; ++kk)
        afr[mt][kk] =
            *(const short8*)(PNb + (size_t)(pw + mt * 16 + mrow) * 128 + kk * 32 + quad * 8);
  }
  for (int it = 0; it < 4; ++it) {
    const int pw = stripe * 512 + it * 128 + wid * 32;
    if (it < 3) {
      const int pn = pw + 128;
#pragma unroll
      for (int mt = 0; mt < 2; ++mt)
#pragma unroll
        for (int kk = 0; kk < 4; ++kk)
          afrn[mt][kk] =
              *(const short8*)(PNb + (size_t)(pn + mt * 16 + mrow) * 128 + kk * 32 + quad * 8);
    }
    float4v acc[2][4];
#pragma unroll
    for (int mt = 0; mt < 2; ++mt)
#pragma unroll
      for (int nt = 0; nt < 4; ++nt) acc[mt][nt] = (float4v){0.f, 0.f, 0.f, 0.f};
#pragma unroll
    for (int kk = 0; kk < 4; ++kk)
#pragma unroll
      for (int mt = 0; mt < 2; ++mt)
#pragma unroll
        for (int nt = 0; nt < 4; ++nt)
          acc[mt][nt] = __builtin_amdgcn_mfma_f32_16x16x32_bf16(afr[mt][kk], bfr[nt][kk],
                                                                acc[mt][nt], 0, 0, 0);
#pragma unroll
    for (int mt = 0; mt < 2; ++mt) {
      const int prow4 = ((pw + mt * 16) >> 2) + quad;
#pragma unroll
      for (int nt = 0; nt < 4; ++nt) {
        const int n = n0 + nt * 16 + mrow;
        short4v pk;
#pragma unroll
        for (int reg = 0; reg < 4; ++reg) {
          float v = acc[mt][nt][reg];
          if (wsel == 0) v *= 0.17677669529663687f;
          // wsel == 1 (K): 1/16 scale folded into Wk at convert time.
          pk[reg] = (short)f2bf(v);
        }
        *(short4v*)(dst + ((size_t)prow4 * 256 + n) * 4) = pk;
      }
    }
#pragma unroll
    for (int mt = 0; mt < 2; ++mt)
#pragma unroll
      for (int kk = 0; kk < 4; ++kk) afr[mt][kk] = afrn[mt][kk];
  }
}

// ---------------- K5 (R19 = R16): V projection, separate kernel -------------
__global__ __launch_bounds__(256) void k_projv(const u16* __restrict__ PNb,
                                               const u16* __restrict__ Wtb,
                                               u16* __restrict__ Vtb) {
  const int t = threadIdx.x;
  const int wid = t >> 6, lane = t & 63;
  const int mrow = lane & 15, quad = lane >> 4;
  const int sc = blockIdx.x;
  const int n0 = blockIdx.y * 64;
  const u16* Wt = Wtb + (size_t)2 * 32768;

  short8 bfr[4][4];
#pragma unroll
  for (int nt = 0; nt < 4; ++nt)
#pragma unroll
    for (int kk = 0; kk < 4; ++kk)
      bfr[nt][kk] = *(const short8*)(Wt + (size_t)(n0 + nt * 16 + mrow) * 128 + kk * 32 + quad * 8);

  short8 afr[2][4], afrn[2][4];
  {
    const int rbase = wid * 32;
#pragma unroll
    for (int mt = 0; mt < 2; ++mt)
#pragma unroll
      for (int kk = 0; kk < 4; ++kk)
        afr[mt][kk] = *(const short8*)(PNb + ((size_t)(rbase + mt * 16 + mrow) * 256 + sc) * 128 +
                                       kk * 32 + quad * 8);
  }
  for (int it = 0; it < 2; ++it) {
    const int rbase = it * 128 + wid * 32;
    if (it == 0) {
      const int rn = 128 + wid * 32;
#pragma unroll
      for (int mt = 0; mt < 2; ++mt)
#pragma unroll
        for (int kk = 0; kk < 4; ++kk)
          afrn[mt][kk] = *(const short8*)(PNb + ((size_t)(rn + mt * 16 + mrow) * 256 + sc) * 128 +
                                          kk * 32 + quad * 8);
    }
    float4v acc[2][4];
#pragma unroll
    for (int mt = 0; mt < 2; ++mt)
#pragma unroll
      for (int nt = 0; nt < 4; ++nt) acc[mt][nt] = (float4v){0.f, 0.f, 0.f, 0.f};
#pragma unroll
    for (int kk = 0; kk < 4; ++kk)
#pragma unroll
      for (int mt = 0; mt < 2; ++mt)
#pragma unroll
        for (int nt = 0; nt < 4; ++nt)
          acc[mt][nt] = __builtin_amdgcn_mfma_f32_16x16x32_bf16(afr[mt][kk], bfr[nt][kk],
                                                                acc[mt][nt], 0, 0, 0);
#pragma unroll
    for (int mt = 0; mt < 2; ++mt) {
      const int j0 = rbase + mt * 16 + quad * 4;
#pragma unroll
      for (int nt = 0; nt < 4; ++nt) {
        const int n = n0 + nt * 16 + mrow;
        const int h = n >> 5, d = n & 31;
        short4v pk;
#pragma unroll
        for (int reg = 0; reg < 4; ++reg) pk[reg] = (short)f2bf(acc[mt][nt][reg]);
        *(short4v*)(Vtb + (size_t)h * 2097152 + (size_t)(sc * 32 + d) * 256 + j0) = pk;
      }
    }
#pragma unroll
    for (int mt = 0; mt < 2; ++mt)
#pragma unroll
      for (int kk = 0; kk < 4; ++kk) afr[mt][kk] = afrn[mt][kk];
  }
}

// ---------------- K6 (R15): logits, split-K z=8 (K=1024 per block) ----------
__global__ __launch_bounds__(256) void k_logits_mfma(const u16* __restrict__ Qr4,
                                                     const u16* __restrict__ Kr4,
                                                     float* __restrict__ Lg2) {
  __shared__ u16 Qs[128 * 72];
  __shared__ u16 Ks[128 * 72];
  const int t = threadIdx.x;
  const int wid = t >> 6, lane = t & 63;
  const int mrow = lane & 15, quad = lane >> 4;
  const int i0 = (blockIdx.x >> 1) * 128, j0 = (blockIdx.x & 1) * 128;
  const int h = blockIdx.y;
  const int z = blockIdx.z;  // 0..7
  const int wi = wid >> 1, wj = wid & 1;
  float4v acc[4][4];
#pragma unroll
  for (int a = 0; a < 4; ++a)
#pragma unroll
    for (int bq = 0; bq < 4; ++bq) acc[a][bq] = (float4v){0.f, 0.f, 0.f, 0.f};

  for (int g = 0; g < 8; ++g) {
    const int sc4 = z * 8 + g;
    for (int sub = 0; sub < 2; ++sub) {
      __syncthreads();
#pragma unroll
      for (int itq = 0; itq < 4; ++itq) {
        int u = itq * 256 + t;
        int i_loc = u >> 3, c16 = sub * 8 + (u & 7);
        size_t qoff = ((size_t)((i0 + i_loc) * 64 + sc4) * 256 + h * 32 + c16 * 2) * 4;
        *(short8*)&Qs[i_loc * 72 + (u & 7) * 8] = *(const short8*)(Qr4 + qoff);
        size_t koff = ((size_t)((j0 + i_loc) * 64 + sc4) * 256 + h * 32 + c16 * 2) * 4;
        *(short8*)&Ks[i_loc * 72 + (u & 7) * 8] = *(const short8*)(Kr4 + koff);
      }
      __syncthreads();
#pragma unroll
      for (int kk = 0; kk < 2; ++kk) {
        short8 afr[4], bfr[4];
#pragma unroll
        for (int mt = 0; mt < 4; ++mt)
          afr[mt] = *(const short8*)&Qs[(wi * 64 + mt * 16 + mrow) * 72 + kk * 32 + quad * 8];
#pragma unroll
        for (int nn = 0; nn < 4; ++nn)
          bfr[nn] = *(const short8*)&Ks[(wj * 64 + nn * 16 + mrow) * 72 + kk * 32 + quad * 8];
#pragma unroll
        for (int mt = 0; mt < 4; ++mt)
#pragma unroll
          for (int nn = 0; nn < 4; ++nn)
            acc[mt][nn] =
                __builtin_amdgcn_mfma_f32_16x16x32_bf16(afr[mt], bfr[nn], acc[mt][nn], 0, 0, 0);
      }
    }
  }
  float* slab = Lg2 + ((size_t)z * 8 + h) * 65536;
#pragma unroll
  for (int mt = 0; mt < 4; ++mt)
#pragma unroll
    for (int nn = 0; nn < 4; ++nn) {
      int j = j0 + wj * 64 + nn * 16 + mrow;
#pragma unroll
      for (int reg = 0; reg < 4; ++reg) {
        int i = i0 + wi * 64 + mt * 16 + quad * 4 + reg;
        slab[(size_t)i * 256 + j] = acc[mt][nn][reg];
      }
    }
}

// ---------------- K7 (R15): softmax, wave-per-row, float4 loads, no LDS -----
__global__ __launch_bounds__(256) void k_softmax(const float* __restrict__ Bp,
                                                 const float* __restrict__ Lg2,
                                                 const int* __restrict__ mask,
                                                 u16* __restrict__ Ab) {
  const int w = threadIdx.x >> 6, lane = threadIdx.x & 63;
  const int i = blockIdx.x * 4 + w, h = blockIdx.y;
  const size_t off = (size_t)h * 65536 + (size_t)i * 256 + lane * 4;
  float4 x4 = *(const float4*)(Bp + off);
  float4 v[8];
#pragma unroll
  for (int z = 0; z < 8; ++z) v[z] = *(const float4*)(Lg2 + (size_t)z * 524288 + off);
  int4 mj = *(const int4*)(mask + lane * 4);
  const bool mi = (mask[i] == 0);
#pragma unroll
  for (int z = 0; z < 8; ++z) {
    x4.x += v[z].x;
    x4.y += v[z].y;
    x4.z += v[z].z;
    x4.w += v[z].w;
  }
  if (mi || mj.x == 0) x4.x = -1e9f;
  if (mi || mj.y == 0) x4.y = -1e9f;
  if (mi || mj.z == 0) x4.z = -1e9f;
  if (mi || mj.w == 0) x4.w = -1e9f;
  float mx = fmaxf(fmaxf(x4.x, x4.y), fmaxf(x4.z, x4.w));
#pragma unroll
  for (int o = 32; o; o >>= 1) mx = fmaxf(mx, __shfl_xor(mx, o));
  float e0 = expf(x4.x - mx), e1 = expf(x4.y - mx), e2 = expf(x4.z - mx), e3 = expf(x4.w - mx);
  float sm = (e0 + e1) + (e2 + e3);
#pragma unroll
  for (int o = 32; o; o >>= 1) sm += __shfl_xor(sm, o);
  short4v pk;
  pk[0] = (short)f2bf(e0 / sm);
  pk[1] = (short)f2bf(e1 / sm);
  pk[2] = (short)f2bf(e2 / sm);
  pk[3] = (short)f2bf(e3 / sm);
  *(short4v*)(Ab + off) = pk;
}

// ---------------- K8 (R18): AV MFMA + fused gate; 8-wave blocks -------------
// grid (16,4,8), 512 threads. One shared As (64x264, staged once, amortized
// over 8 waves); per-wave Ts (32x72). LDS 70.7KB -> 2 blocks/CU, 16 waves/CU.
__global__ __launch_bounds__(512) void k_av_mfma(const u16* __restrict__ Ab,
                                                 const u16* __restrict__ Vtb,
                                                 const u16* __restrict__ PNb,
                                                 const u16* __restrict__ Wtb,
                                                 const float* __restrict__ bg,
                                                 u16* __restrict__ GOb) {
  __shared__ u16 As[64 * 264];
  __shared__ u16 Ts[8][32 * 72];
  const int t = threadIdx.x;
  const int wid = t >> 6, lane = t & 63;
  const int mrow = lane & 15, quad = lane >> 4;
  const int h = blockIdx.z;
  const int i0 = blockIdx.y * 64;
  const u16* ag = Ab + (size_t)h * 65536 + (size_t)i0 * 256;
#pragma unroll
  for (int u = 0; u < 4; ++u) {
    int id = u * 512 + t;
    int rr = id >> 5, c8 = (id & 31) * 8;
    *(short8*)&As[rr * 264 + c8] = *(const short8*)(ag + (size_t)rr * 256 + c8);
  }
  __syncthreads();
  const u16* vg = Vtb + (size_t)h * 2097152;
  const u16* Wg3 = Wtb + (size_t)3 * 32768;
  // hoisted gate B-frags (Wg cols e = h*32 + eh*16 + mrow) + bg
  short8 bfrg[2][4];
  float bgv2[2];
#pragma unroll
  for (int eh = 0; eh < 2; ++eh) {
#pragma unroll
    for (int kk = 0; kk < 4; ++kk)
      bfrg[eh][kk] =
          *(const short8*)(Wg3 + (size_t)(h * 32 + eh * 16 + mrow) * 128 + kk * 32 + quad * 8);
    bgv2[eh] = bg[h * 32 + eh * 16 + mrow];
  }
  u16* tw = &Ts[wid][0];
  const int c = lane & 7, lr = lane >> 3;
  const int nbase = blockIdx.x * 512 + wid * 64;  // 64 n-values per wave
  const int kslot0 = nbase >> 5;
  // ---- gate tiles for this wave's 2 kslots ----
  short4v gbf[2][4][2];
  {
    float4v gacc[2][4][2];
#pragma unroll
    for (int ks = 0; ks < 2; ++ks)
#pragma unroll
      for (int mt = 0; mt < 4; ++mt)
#pragma unroll
        for (int eh = 0; eh < 2; ++eh) gacc[ks][mt][eh] = (float4v){0.f, 0.f, 0.f, 0.f};
#pragma unroll
    for (int ks = 0; ks < 2; ++ks) {
#pragma unroll
      for (int mt = 0; mt < 4; ++mt) {
        const int p0 = (kslot0 + ks) * 256 + i0 + mt * 16;
        short8 afg[4];
#pragma unroll
        for (int kk = 0; kk < 4; ++kk)
          afg[kk] = *(const short8*)(PNb + (size_t)(p0 + mrow) * 128 + kk * 32 + quad * 8);
#pragma unroll
        for (int kk = 0; kk < 4; ++kk)
#pragma unroll
          for (int eh = 0; eh < 2; ++eh)
            gacc[ks][mt][eh] = __builtin_amdgcn_mfma_f32_16x16x32_bf16(afg[kk], bfrg[eh][kk],
                                                                       gacc[ks][mt][eh], 0, 0, 0);
      }
    }
#pragma unroll
    for (int ks = 0; ks < 2; ++ks)
#pragma unroll
      for (int mt = 0; mt < 4; ++mt)
#pragma unroll
        for (int eh = 0; eh < 2; ++eh) {
          short4v pk;
#pragma unroll
          for (int reg = 0; reg < 4; ++reg) {
            float ex = __expf(-(gacc[ks][mt][eh][reg] + bgv2[eh]));
            pk[reg] = (short)f2bf(__builtin_amdgcn_rcpf(1.0f + ex));
          }
          gbf[ks][mt][eh] = pk;
        }
  }
  // ---- AV MFMA (A-frags from shared As) ----
  float4v acc[4][4];
#pragma unroll
  for (int a = 0; a < 4; ++a)
#pragma unroll
    for (int bq = 0; bq < 4; ++bq) acc[a][bq] = (float4v){0.f, 0.f, 0.f, 0.f};
#pragma unroll
  for (int kk = 0; kk < 8; ++kk) {
    short8 afr[4], bfr[4];
#pragma unroll
    for (int mt = 0; mt < 4; ++mt)
      afr[mt] = *(const short8*)&As[(mt * 16 + mrow) * 264 + kk * 32 + quad * 8];
#pragma unroll
    for (int nn = 0; nn < 4; ++nn)
      bfr[nn] = *(const short8*)(vg + (size_t)(nbase + nn * 16 + mrow) * 256 + kk * 32 + quad * 8);
#pragma unroll
    for (int mt = 0; mt < 4; ++mt)
#pragma unroll
      for (int nn = 0; nn < 4; ++nn)
        acc[mt][nn] = __builtin_amdgcn_mfma_f32_16x16x32_bf16(afr[mt], bfr[nn], acc[mt][nn], 0, 0, 0);
  }
  // ---- gate + LDS transpose + coalesced store, two 32-row halves ----
#pragma unroll
  for (int mth = 0; mth < 2; ++mth) {
#pragma unroll
    for (int mt2 = 0; mt2 < 2; ++mt2) {
      const int mt = mth * 2 + mt2;
#pragma unroll
      for (int nn = 0; nn < 4; ++nn) {
        short4v g4 = gbf[nn >> 1][mt][nn & 1];
        const int il0 = mt2 * 16 + quad * 4;
        const int nl = nn * 16 + mrow;
#pragma unroll
        for (int reg = 0; reg < 4; ++reg) {
          float gv = bf2f((u16)g4[reg]);
          tw[(il0 + reg) * 72 + nl] = f2bf(acc[mt][nn][reg] * gv);
        }
      }
    }
    asm volatile("s_waitcnt lgkmcnt(0)" ::: "memory");
#pragma unroll
    for (int y = 0; y < 4; ++y) {
      const int ill = y * 8 + lr;
      short8 val = *(const short8*)(tw + ill * 72 + c * 8);
      const int i = i0 + mth * 32 + ill;
      const int kslot = kslot0 + (c >> 2);
      size_t idx = ((size_t)i * 256 + kslot) * 256 + h * 32 + (c & 3) * 8;
      *(short8*)(GOb + idx) = val;
    }
    if (mth == 0) asm volatile("s_waitcnt lgkmcnt(0)" ::: "memory");
  }
}

// ---------------- K9: output proj (MFMA) + bias + transpose + mask ----------
__global__ __launch_bounds__(256) void k_out_mfma(const u16* __restrict__ GOb,
                                                  const u16* __restrict__ Wotb,
                                                  const float* __restrict__ bo,
                                                  const int* __restrict__ mask,
                                                  float* __restrict__ out) {
  const int wid = threadIdx.x >> 6, lane = threadIdx.x & 63;
  const int mrow = lane & 15, quad = lane >> 4;
  const int m0 = blockIdx.x * 128 + wid * 32;
  short8 afr[2][8];
#pragma unroll
  for (int mt = 0; mt < 2; ++mt) {
    const u16* ar = GOb + (size_t)(m0 + mt * 16 + mrow) * 256 + quad * 8;
#pragma unroll
    for (int kk = 0; kk < 8; ++kk) afr[mt][kk] = *(const short8*)(ar + kk * 32);
  }
  for (int nt = 0; nt < 8; ++nt) {
    float4v acc[2];
    acc[0] = (float4v){0.f, 0.f, 0.f, 0.f};
    acc[1] = (float4v){0.f, 0.f, 0.f, 0.f};
    const u16* br = Wotb + (size_t)(nt * 16 + mrow) * 256 + quad * 8;
#pragma unroll
    for (int kk = 0; kk < 8; ++kk) {
      short8 bfr = *(const short8*)(br + kk * 32);
#pragma unroll
      for (int mt = 0; mt < 2; ++mt)
        acc[mt] = __builtin_amdgcn_mfma_f32_16x16x32_bf16(afr[mt][kk], bfr, acc[mt], 0, 0, 0);
    }
    const int c = nt * 16 + mrow;
    float bov = bo[c];
#pragma unroll
    for (int mt = 0; mt < 2; ++mt) {
#pragma unroll
      for (int reg = 0; reg < 4; ++reg) {
        int m = m0 + mt * 16 + quad * 4 + reg;  // = i*256 + k
        int i = m >> 8, kq = m & 255;
        float v = acc[mt][reg] + bov;
        bool z = (mask[i] == 0) || (mask[kq] == 0);
        __builtin_nontemporal_store(z ? 0.f : v, &out[((size_t)kq * 256 + i) * 128 + c]);
      }
    }
  }
}

extern "C" void kernel_launch(void* const* d_in, const int* in_sizes, int n_in,
                              void* d_out, int out_size, void* d_ws, size_t ws_size,
                              hipStream_t stream) {
  const float* pair = (const float*)d_in[0];
  const float* bias = (const float*)d_in[1];
  const int* mask = (const int*)d_in[2];
  const float* g_pair = (const float*)d_in[3];
  const float* b_pair = (const float*)d_in[4];
  const float* g_bias = (const float*)d_in[5];
  const float* b_bias = (const float*)d_in[6];
  const float* Wq = (const float*)d_in[7];
  const float* Wk = (const float*)d_in[8];
  const float* Wv = (const float*)d_in[9];
  const float* Wb = (const float*)d_in[10];
  const float* Wg = (const float*)d_in[11];
  const float* bg = (const float*)d_in[12];
  const float* Wo = (const float*)d_in[13];
  const float* bo = (const float*)d_in[14];
  float* out = (float*)d_out;
  char* ws = (char*)d_ws;

  u16* PNb = (u16*)(ws + 0);
  u16* Qr4 = (u16*)(ws + 16777216);
  u16* Kr4 = (u16*)(ws + 50331648);
  u16* Vtb = (u16*)(ws + 83886080);
  u16* GOb = (u16*)(ws + 150994944);
  float* Bp = (float*)(ws + 184549376);
  u16* Ab = (u16*)(ws + 186646528);
  u16* Wtb = (u16*)(ws + 187695104);
  u16* Wotb = (u16*)(ws + 187957248);
  float* Lg2 = (float*)(ws + 188022784);

  k_pre<<<2688, 256, 0, stream>>>(pair, g_pair, b_pair, PNb, bias, g_bias, b_bias, Wb, Bp,
                                  Wq, Wk, Wv, Wg, Wo, Wtb, Wotb);
  k_proj_qkg<<<dim3(128, 4, 2), 256, 0, stream>>>(PNb, Wtb, Qr4, Kr4);
  k_projv<<<dim3(256, 4), 256, 0, stream>>>(PNb, Wtb, Vtb);
  k_logits_mfma<<<dim3(4, 8, 8), 256, 0, stream>>>(Qr4, Kr4, Lg2);
  k_softmax<<<dim3(64, 8), 256, 0, stream>>>(Bp, Lg2, mask, Ab);
  k_av_mfma<<<dim3(16, 4, 8), 512, 0, stream>>>(Ab, Vtb, PNb, Wtb, bg, GOb);
  k_out_mfma<<<512, 256, 0, stream>>>(GOb, Wotb, bo, mask, out);
}

// Round 10
// 294.034 us; speedup vs baseline: 1.0192x; 1.0192x over previous
//
#include <hip/hip_runtime.h>
#include <math.h>

// B=1, L=256, DP=128, DB=128, H=8, DH=32, H*DH=256
// bf16 MFMA 16x16x32. Q/K use a 4-row-tiled layout X4[(p>>2)][n][p&3];
// V projection stores D-fragments directly into Vtb. NO atomics anywhere.
// R11: K-scale folded into Wk; fast sigmoid; k_av LDS-transposed stores.
// R12: proj dbuf A-frags; stage-1 merged into k_pre.
// R14: k_pre structural ILP (LDS Wb, sched_barrier pin, 2 rows/thread).
// R15: gate fused into k_av (G2 dead); logits z=8; wave-per-row softmax.
// R16: k_av 4-wave, nt4 split across blocks, Ts halved (52.2KB) -> 44us. BEST.
// R17 REGRESSED (59us): no-As exposed L2 latency on MFMA A-chain.
// R18 REGRESSED (59us, masked by merged k_proj): 8-wave blocks doubled the
//      barrier scope + halved blocks/CU; k_proj merge inflated VGPR 88->140.
// R19: projections re-split (good); k_av 8-wave kept (bad, now measured 59).
// R20: revert k_av to R16's EXACT 4-wave kernel (measured 44us). Composition
//      is now measured-best-per-kernel. Bit-identical values.
//
// k_av variant ledger (measured): R16 4-wave=44 | R15 1blk/CU=48 |
//                                 R17 no-As=59 | R18 8-wave=59.
//
// Fragment layouts (HW-verified):
//   A-frag: lane holds A[m=lane&15][k=(lane>>4)*8+j], j=0..7 (16B)
//   B-frag: lane holds B[k=(lane>>4)*8+j][n=lane&15]
//   D:      lane holds D[row=(lane>>4)*4+reg][col=lane&15]
//
// Workspace (byte offsets):
//   PNb  u16 [65536][128]     @ 0            16,777,216   LN(pair), row p=r*256+sc
//   Qr4  u16 tiled [16384][256][4] @ 16777216 33,554,432  (p>>2, n, p&3), p=(i,sc)
//   Kr4  u16 tiled             @ 50331648    33,554,432
//   Vtb  u16 [8][8192][256]   @ 83886080     33,554,432   [h][k*32+d][j]
//   GOb  u16 [65536][256]     @ 150994944    33,554,432   row = i*256+k
//   Bp   f32 [8][256][256]    @ 184549376     2,097,152
//   Ab   u16 [8][256][256]    @ 186646528     1,048,576
//   Wtb  u16 [4][256][128]    @ 187695104       262,144   W{q,k,v,g}^T [n][k]
//   Wotb u16 [128][256]       @ 187957248        65,536   Wo^T [c][e]
//   Lg2  f32 [8][8][256][256] @ 188022784    16,777,216   split-K logit slices

typedef unsigned short u16;
typedef __attribute__((ext_vector_type(8))) short short8;
typedef __attribute__((ext_vector_type(4))) short short4v;
typedef __attribute__((ext_vector_type(4))) float float4v;

__device__ __forceinline__ u16 f2bf(float f) {
  unsigned int u = __float_as_uint(f);
  u += 0x7FFFu + ((u >> 16) & 1u);
  return (u16)(u >> 16);
}
__device__ __forceinline__ float bf2f(u16 h) {
  return __uint_as_float(((unsigned int)h) << 16);
}

// ---------------- K_pre (R14): grid-union of ln / lnbias+bproj / wcvt -------
__global__ __launch_bounds__(256, 4) void k_pre(
    const float* __restrict__ x1, const float* __restrict__ g1,
    const float* __restrict__ b1, u16* __restrict__ y1,
    const float* __restrict__ x2, const float* __restrict__ g2,
    const float* __restrict__ b2, const float* __restrict__ Wb,
    float* __restrict__ Bp,
    const float* __restrict__ Wq, const float* __restrict__ Wk,
    const float* __restrict__ Wv, const float* __restrict__ Wg,
    const float* __restrict__ Wo, u16* __restrict__ Wtb, u16* __restrict__ Wotb) {
  __shared__ float wbs[128 * 9];  // lnbias branch only: Wb staged, pitch 9
  const int bid = blockIdx.x;
  const int t = threadIdx.x;
  if (bid < 1024) {
    // ---- LayerNorm(pair) -> PNb, 2 independent rows per thread ----
    const int row = t >> 3, h = t & 7;
    const int p0 = bid * 64 + row;
    const int p1 = p0 + 32;
    const float* rpA = x1 + (size_t)p0 * 128 + h * 16;
    const float* rpB = x1 + (size_t)p1 * 128 + h * 16;
    float4 xa[4], xb[4], gv4[4], bv4[4];
#pragma unroll
    for (int i = 0; i < 4; ++i) xa[i] = ((const float4*)rpA)[i];
#pragma unroll
    for (int i = 0; i < 4; ++i) xb[i] = ((const float4*)rpB)[i];
#pragma unroll
    for (int i = 0; i < 4; ++i) {
      gv4[i] = ((const float4*)(g1 + h * 16))[i];
      bv4[i] = ((const float4*)(b1 + h * 16))[i];
    }
    __builtin_amdgcn_sched_barrier(0);  // pin: all 16 loads issued above
    float sA = 0.f, ssA = 0.f, sB = 0.f, ssB = 0.f;
#pragma unroll
    for (int i = 0; i < 4; ++i) {
      sA += (xa[i].x + xa[i].y) + (xa[i].z + xa[i].w);
      ssA += (xa[i].x * xa[i].x + xa[i].y * xa[i].y) + (xa[i].z * xa[i].z + xa[i].w * xa[i].w);
      sB += (xb[i].x + xb[i].y) + (xb[i].z + xb[i].w);
      ssB += (xb[i].x * xb[i].x + xb[i].y * xb[i].y) + (xb[i].z * xb[i].z + xb[i].w * xb[i].w);
    }
#pragma unroll
    for (int off = 1; off <= 4; off <<= 1) {
      sA += __shfl_xor(sA, off);
      ssA += __shfl_xor(ssA, off);
      sB += __shfl_xor(sB, off);
      ssB += __shfl_xor(ssB, off);
    }
    float mA = sA * (1.0f / 128.0f);
    float invA = rsqrtf(ssA * (1.0f / 128.0f) - mA * mA + 1e-5f);
    float mB = sB * (1.0f / 128.0f);
    float invB = rsqrtf(ssB * (1.0f / 128.0f) - mB * mB + 1e-5f);
    short8 oA[2], oB[2];
#pragma unroll
    for (int i4 = 0; i4 < 4; ++i4) {
      float4 gv = gv4[i4], bv = bv4[i4];
      oA[i4 >> 1][(i4 & 1) * 4 + 0] = (short)f2bf((xa[i4].x - mA) * invA * gv.x + bv.x);
      oA[i4 >> 1][(i4 & 1) * 4 + 1] = (short)f2bf((xa[i4].y - mA) * invA * gv.y + bv.y);
      oA[i4 >> 1][(i4 & 1) * 4 + 2] = (short)f2bf((xa[i4].z - mA) * invA * gv.z + bv.z);
      oA[i4 >> 1][(i4 & 1) * 4 + 3] = (short)f2bf((xa[i4].w - mA) * invA * gv.w + bv.w);
      oB[i4 >> 1][(i4 & 1) * 4 + 0] = (short)f2bf((xb[i4].x - mB) * invB * gv.x + bv.x);
      oB[i4 >> 1][(i4 & 1) * 4 + 1] = (short)f2bf((xb[i4].y - mB) * invB * gv.y + bv.y);
      oB[i4 >> 1][(i4 & 1) * 4 + 2] = (short)f2bf((xb[i4].z - mB) * invB * gv.z + bv.z);
      oB[i4 >> 1][(i4 & 1) * 4 + 3] = (short)f2bf((xb[i4].w - mB) * invB * gv.w + bv.w);
    }
    u16* opA = y1 + (size_t)p0 * 128 + h * 16;
    *(short8*)opA = oA[0];
    *(short8*)(opA + 8) = oA[1];
    u16* opB = y1 + (size_t)p1 * 128 + h * 16;
    *(short8*)opB = oB[0];
    *(short8*)(opB + 8) = oB[1];
  } else if (bid < 2048) {
    // ---- LN(bias) + Wb proj -> Bp, 2 rows/thread, Wb from LDS ----
    {
      float4 wv = ((const float4*)Wb)[t];
      const int k = t >> 1, e0 = (t & 1) * 4;
      wbs[k * 9 + e0 + 0] = wv.x;
      wbs[k * 9 + e0 + 1] = wv.y;
      wbs[k * 9 + e0 + 2] = wv.z;
      wbs[k * 9 + e0 + 3] = wv.w;
    }
    const int row = t >> 3, h = t & 7;
    const int p0 = (bid - 1024) * 64 + row;
    const int p1 = p0 + 32;
    const int r0 = p0 >> 8, sc0 = p0 & 255;
    const int r1 = p1 >> 8, sc1 = p1 & 255;
    const float* rpA = x2 + (size_t)p0 * 128 + h * 16;
    const float* rpB = x2 + (size_t)p1 * 128 + h * 16;
    float4 xa[4], xb[4], gv4[4], bv4[4];
#pragma unroll
    for (int i = 0; i < 4; ++i) xa[i] = ((const float4*)rpA)[i];
#pragma unroll
    for (int i = 0; i < 4; ++i) xb[i] = ((const float4*)rpB)[i];
#pragma unroll
    for (int i = 0; i < 4; ++i) {
      gv4[i] = ((const float4*)(g2 + h * 16))[i];
      bv4[i] = ((const float4*)(b2 + h * 16))[i];
    }
    __builtin_amdgcn_sched_barrier(0);
    __syncthreads();  // wbs ready
    float sA = 0.f, ssA = 0.f, sB = 0.f, ssB = 0.f;
#pragma unroll
    for (int i = 0; i < 4; ++i) {
      sA += (xa[i].x + xa[i].y) + (xa[i].z + xa[i].w);
      ssA += (xa[i].x * xa[i].x + xa[i].y * xa[i].y) + (xa[i].z * xa[i].z + xa[i].w * xa[i].w);
      sB += (xb[i].x + xb[i].y) + (xb[i].z + xb[i].w);
      ssB += (xb[i].x * xb[i].x + xb[i].y * xb[i].y) + (xb[i].z * xb[i].z + xb[i].w * xb[i].w);
    }
#pragma unroll
    for (int off = 1; off <= 4; off <<= 1) {
      sA += __shfl_xor(sA, off);
      ssA += __shfl_xor(ssA, off);
      sB += __shfl_xor(sB, off);
      ssB += __shfl_xor(ssB, off);
    }
    float mA = sA * (1.0f / 128.0f);
    float invA = rsqrtf(ssA * (1.0f / 128.0f) - mA * mA + 1e-5f);
    float mB = sB * (1.0f / 128.0f);
    float invB = rsqrtf(ssB * (1.0f / 128.0f) - mB * mB + 1e-5f);
    float pa[8], pb[8];
#pragma unroll
    for (int e = 0; e < 8; ++e) {
      pa[e] = 0.f;
      pb[e] = 0.f;
    }
#pragma unroll
    for (int i4 = 0; i4 < 4; ++i4) {
      float4 gv = gv4[i4], bv = bv4[i4];
      float xsA[4] = {xa[i4].x, xa[i4].y, xa[i4].z, xa[i4].w};
      float xsB[4] = {xb[i4].x, xb[i4].y, xb[i4].z, xb[i4].w};
      float gs[4] = {gv.x, gv.y, gv.z, gv.w};
      float bs[4] = {bv.x, bv.y, bv.z, bv.w};
#pragma unroll
      for (int q = 0; q < 4; ++q) {
        const int k = h * 16 + i4 * 4 + q;
        float xnA = (xsA[q] - mA) * invA * gs[q] + bs[q];
        float xnB = (xsB[q] - mB) * invB * gs[q] + bs[q];
        const float* wr = &wbs[k * 9];
#pragma unroll
        for (int e = 0; e < 8; ++e) {
          float w = wr[e];
          pa[e] += xnA * w;
          pb[e] += xnB * w;
        }
      }
    }
#pragma unroll
    for (int off = 1; off <= 4; off <<= 1) {
#pragma unroll
      for (int e = 0; e < 8; ++e) {
        pa[e] += __shfl_xor(pa[e], off);
        pb[e] += __shfl_xor(pb[e], off);
      }
    }
    float vA = (h == 0) ? pa[0]
             : (h == 1) ? pa[1]
             : (h == 2) ? pa[2]
             : (h == 3) ? pa[3]
             : (h == 4) ? pa[4]
             : (h == 5) ? pa[5]
             : (h == 6) ? pa[6]
                        : pa[7];
    float vB = (h == 0) ? pb[0]
             : (h == 1) ? pb[1]
             : (h == 2) ? pb[2]
             : (h == 3) ? pb[3]
             : (h == 4) ? pb[4]
             : (h == 5) ? pb[5]
             : (h == 6) ? pb[6]
                        : pb[7];
    Bp[(size_t)h * 65536 + (size_t)sc0 * 256 + r0] = vA;
    Bp[(size_t)h * 65536 + (size_t)sc1 * 256 + r1] = vB;
  } else {
    // ---- weight convert/transpose: coalesced loads, scattered stores ----
    int idx = (bid - 2048) * 256 + t;
    if (idx < 131072) {
      int w = idx >> 15, r = idx & 32767;
      int k = r >> 8, n = r & 255;
      const float* W = (w == 0) ? Wq : (w == 1) ? Wk : (w == 2) ? Wv : Wg;
      const float sW = (w == 1) ? 0.0625f : 1.0f;
      Wtb[(size_t)w * 32768 + n * 128 + k] = f2bf(W[k * 256 + n] * sW);
    } else {
      int r = idx - 131072;
      int e = r >> 7, c = r & 127;
      Wotb[c * 256 + e] = f2bf(Wo[e * 128 + c]);
    }
  }
}

// ---------------- K4 (R16): Q/K projections, separate kernel ----------------
// grid (128 stripes of 512 rows, 4 col-quarters, 2 weights). Dbuf A-frags.
__global__ __launch_bounds__(256) void k_proj_qkg(const u16* __restrict__ PNb,
                                                  const u16* __restrict__ Wtb,
                                                  u16* __restrict__ Qr4,
                                                  u16* __restrict__ Kr4) {
  const int t = threadIdx.x;
  const int wid = t >> 6, lane = t & 63;
  const int mrow = lane & 15, quad = lane >> 4;
  const int stripe = blockIdx.x;
  const int n0 = blockIdx.y * 64;
  const int wsel = blockIdx.z;  // 0:Q 1:K
  const u16* Wt = Wtb + (size_t)wsel * 32768;
  u16* dst = (wsel == 0) ? Qr4 : Kr4;

  short8 bfr[4][4];
#pragma unroll
  for (int nt = 0; nt < 4; ++nt)
#pragma unroll
    for (int kk = 0; kk < 4; ++kk)
      bfr[nt][kk] = *(const short8*)(Wt + (size_t)(n0 + nt * 16 + mrow) * 128 + kk * 32 + quad * 8);

  short8 afr[2][4], afrn[2][4];
  {
    const int pw = stripe * 512 + wid * 32;
#pragma unroll
    for (int mt = 0; mt < 2; ++mt)
#pragma unroll
      for (int kk = 0; kk < 4; ++kk)
        afr[mt][kk] =
            *(const short8*)(PNb + (size_t)(pw + mt * 16 + mrow) * 128 + kk * 32 + quad * 8);
  }
  for (int it = 0; it < 4; ++it) {
    const int pw = stripe * 512 + it * 128 + wid * 32;
    if (it < 3) {
      const int pn = pw + 128;
#pragma unroll
      for (int mt = 0; mt < 2; ++mt)
#pragma unroll
        for (int kk = 0; kk < 4; ++kk)
          afrn[mt][kk] =
              *(const short8*)(PNb + (size_t)(pn + mt * 16 + mrow) * 128 + kk * 32 + quad * 8);
    }
    float4v acc[2][4];
#pragma unroll
    for (int mt = 0; mt < 2; ++mt)
#pragma unroll
      for (int nt = 0; nt < 4; ++nt) acc[mt][nt] = (float4v){0.f, 0.f, 0.f, 0.f};
#pragma unroll
    for (int kk = 0; kk < 4; ++kk)
#pragma unroll
      for (int mt = 0; mt < 2; ++mt)
#pragma unroll
        for (int nt = 0; nt < 4; ++nt)
          acc[mt][nt] = __builtin_amdgcn_mfma_f32_16x16x32_bf16(afr[mt][kk], bfr[nt][kk],
                                                                acc[mt][nt], 0, 0, 0);
#pragma unroll
    for (int mt = 0; mt < 2; ++mt) {
      const int prow4 = ((pw + mt * 16) >> 2) + quad;
#pragma unroll
      for (int nt = 0; nt < 4; ++nt) {
        const int n = n0 + nt * 16 + mrow;
        short4v pk;
#pragma unroll
        for (int reg = 0; reg < 4; ++reg) {
          float v = acc[mt][nt][reg];
          if (wsel == 0) v *= 0.17677669529663687f;
          // wsel == 1 (K): 1/16 scale folded into Wk at convert time.
          pk[reg] = (short)f2bf(v);
        }
        *(short4v*)(dst + ((size_t)prow4 * 256 + n) * 4) = pk;
      }
    }
#pragma unroll
    for (int mt = 0; mt < 2; ++mt)
#pragma unroll
      for (int kk = 0; kk < 4; ++kk) afr[mt][kk] = afrn[mt][kk];
  }
}

// ---------------- K5 (R16): V projection, separate kernel -------------------
__global__ __launch_bounds__(256) void k_projv(const u16* __restrict__ PNb,
                                               const u16* __restrict__ Wtb,
                                               u16* __restrict__ Vtb) {
  const int t = threadIdx.x;
  const int wid = t >> 6, lane = t & 63;
  const int mrow = lane & 15, quad = lane >> 4;
  const int sc = blockIdx.x;
  const int n0 = blockIdx.y * 64;
  const u16* Wt = Wtb + (size_t)2 * 32768;

  short8 bfr[4][4];
#pragma unroll
  for (int nt = 0; nt < 4; ++nt)
#pragma unroll
    for (int kk = 0; kk < 4; ++kk)
      bfr[nt][kk] = *(const short8*)(Wt + (size_t)(n0 + nt * 16 + mrow) * 128 + kk * 32 + quad * 8);

  short8 afr[2][4], afrn[2][4];
  {
    const int rbase = wid * 32;
#pragma unroll
    for (int mt = 0; mt < 2; ++mt)
#pragma unroll
      for (int kk = 0; kk < 4; ++kk)
        afr[mt][kk] = *(const short8*)(PNb + ((size_t)(rbase + mt * 16 + mrow) * 256 + sc) * 128 +
                                       kk * 32 + quad * 8);
  }
  for (int it = 0; it < 2; ++it) {
    const int rbase = it * 128 + wid * 32;
    if (it == 0) {
      const int rn = 128 + wid * 32;
#pragma unroll
      for (int mt = 0; mt < 2; ++mt)
#pragma unroll
        for (int kk = 0; kk < 4; ++kk)
          afrn[mt][kk] = *(const short8*)(PNb + ((size_t)(rn + mt * 16 + mrow) * 256 + sc) * 128 +
                                          kk * 32 + quad * 8);
    }
    float4v acc[2][4];
#pragma unroll
    for (int mt = 0; mt < 2; ++mt)
#pragma unroll
      for (int nt = 0; nt < 4; ++nt) acc[mt][nt] = (float4v){0.f, 0.f, 0.f, 0.f};
#pragma unroll
    for (int kk = 0; kk < 4; ++kk)
#pragma unroll
      for (int mt = 0; mt < 2; ++mt)
#pragma unroll
        for (int nt = 0; nt < 4; ++nt)
          acc[mt][nt] = __builtin_amdgcn_mfma_f32_16x16x32_bf16(afr[mt][kk], bfr[nt][kk],
                                                                acc[mt][nt], 0, 0, 0);
#pragma unroll
    for (int mt = 0; mt < 2; ++mt) {
      const int j0 = rbase + mt * 16 + quad * 4;
#pragma unroll
      for (int nt = 0; nt < 4; ++nt) {
        const int n = n0 + nt * 16 + mrow;
        const int h = n >> 5, d = n & 31;
        short4v pk;
#pragma unroll
        for (int reg = 0; reg < 4; ++reg) pk[reg] = (short)f2bf(acc[mt][nt][reg]);
        *(short4v*)(Vtb + (size_t)h * 2097152 + (size_t)(sc * 32 + d) * 256 + j0) = pk;
      }
    }
#pragma unroll
    for (int mt = 0; mt < 2; ++mt)
#pragma unroll
      for (int kk = 0; kk < 4; ++kk) afr[mt][kk] = afrn[mt][kk];
  }
}

// ---------------- K6 (R15): logits, split-K z=8 (K=1024 per block) ----------
__global__ __launch_bounds__(256) void k_logits_mfma(const u16* __restrict__ Qr4,
                                                     const u16* __restrict__ Kr4,
                                                     float* __restrict__ Lg2) {
  __shared__ u16 Qs[128 * 72];
  __shared__ u16 Ks[128 * 72];
  const int t = threadIdx.x;
  const int wid = t >> 6, lane = t & 63;
  const int mrow = lane & 15, quad = lane >> 4;
  const int i0 = (blockIdx.x >> 1) * 128, j0 = (blockIdx.x & 1) * 128;
  const int h = blockIdx.y;
  const int z = blockIdx.z;  // 0..7
  const int wi = wid >> 1, wj = wid & 1;
  float4v acc[4][4];
#pragma unroll
  for (int a = 0; a < 4; ++a)
#pragma unroll
    for (int bq = 0; bq < 4; ++bq) acc[a][bq] = (float4v){0.f, 0.f, 0.f, 0.f};

  for (int g = 0; g < 8; ++g) {
    const int sc4 = z * 8 + g;
    for (int sub = 0; sub < 2; ++sub) {
      __syncthreads();
#pragma unroll
      for (int itq = 0; itq < 4; ++itq) {
        int u = itq * 256 + t;
        int i_loc = u >> 3, c16 = sub * 8 + (u & 7);
        size_t qoff = ((size_t)((i0 + i_loc) * 64 + sc4) * 256 + h * 32 + c16 * 2) * 4;
        *(short8*)&Qs[i_loc * 72 + (u & 7) * 8] = *(const short8*)(Qr4 + qoff);
        size_t koff = ((size_t)((j0 + i_loc) * 64 + sc4) * 256 + h * 32 + c16 * 2) * 4;
        *(short8*)&Ks[i_loc * 72 + (u & 7) * 8] = *(const short8*)(Kr4 + koff);
      }
      __syncthreads();
#pragma unroll
      for (int kk = 0; kk < 2; ++kk) {
        short8 afr[4], bfr[4];
#pragma unroll
        for (int mt = 0; mt < 4; ++mt)
          afr[mt] = *(const short8*)&Qs[(wi * 64 + mt * 16 + mrow) * 72 + kk * 32 + quad * 8];
#pragma unroll
        for (int nn = 0; nn < 4; ++nn)
          bfr[nn] = *(const short8*)&Ks[(wj * 64 + nn * 16 + mrow) * 72 + kk * 32 + quad * 8];
#pragma unroll
        for (int mt = 0; mt < 4; ++mt)
#pragma unroll
          for (int nn = 0; nn < 4; ++nn)
            acc[mt][nn] =
                __builtin_amdgcn_mfma_f32_16x16x32_bf16(afr[mt], bfr[nn], acc[mt][nn], 0, 0, 0);
      }
    }
  }
  float* slab = Lg2 + ((size_t)z * 8 + h) * 65536;
#pragma unroll
  for (int mt = 0; mt < 4; ++mt)
#pragma unroll
    for (int nn = 0; nn < 4; ++nn) {
      int j = j0 + wj * 64 + nn * 16 + mrow;
#pragma unroll
      for (int reg = 0; reg < 4; ++reg) {
        int i = i0 + wi * 64 + mt * 16 + quad * 4 + reg;
        slab[(size_t)i * 256 + j] = acc[mt][nn][reg];
      }
    }
}

// ---------------- K7 (R15): softmax, wave-per-row, float4 loads, no LDS -----
__global__ __launch_bounds__(256) void k_softmax(const float* __restrict__ Bp,
                                                 const float* __restrict__ Lg2,
                                                 const int* __restrict__ mask,
                                                 u16* __restrict__ Ab) {
  const int w = threadIdx.x >> 6, lane = threadIdx.x & 63;
  const int i = blockIdx.x * 4 + w, h = blockIdx.y;
  const size_t off = (size_t)h * 65536 + (size_t)i * 256 + lane * 4;
  float4 x4 = *(const float4*)(Bp + off);
  float4 v[8];
#pragma unroll
  for (int z = 0; z < 8; ++z) v[z] = *(const float4*)(Lg2 + (size_t)z * 524288 + off);
  int4 mj = *(const int4*)(mask + lane * 4);
  const bool mi = (mask[i] == 0);
#pragma unroll
  for (int z = 0; z < 8; ++z) {
    x4.x += v[z].x;
    x4.y += v[z].y;
    x4.z += v[z].z;
    x4.w += v[z].w;
  }
  if (mi || mj.x == 0) x4.x = -1e9f;
  if (mi || mj.y == 0) x4.y = -1e9f;
  if (mi || mj.z == 0) x4.z = -1e9f;
  if (mi || mj.w == 0) x4.w = -1e9f;
  float mx = fmaxf(fmaxf(x4.x, x4.y), fmaxf(x4.z, x4.w));
#pragma unroll
  for (int o = 32; o; o >>= 1) mx = fmaxf(mx, __shfl_xor(mx, o));
  float e0 = expf(x4.x - mx), e1 = expf(x4.y - mx), e2 = expf(x4.z - mx), e3 = expf(x4.w - mx);
  float sm = (e0 + e1) + (e2 + e3);
#pragma unroll
  for (int o = 32; o; o >>= 1) sm += __shfl_xor(sm, o);
  short4v pk;
  pk[0] = (short)f2bf(e0 / sm);
  pk[1] = (short)f2bf(e1 / sm);
  pk[2] = (short)f2bf(e2 / sm);
  pk[3] = (short)f2bf(e3 / sm);
  *(short4v*)(Ab + off) = pk;
}

// ---------------- K8 (R20 = R16): AV MFMA + fused gate, 4-wave blocks -------
// grid (32,4,8), 256 threads. As staged per block; per-wave Ts (32x72).
// LDS 52,224 B -> 3 blocks/CU, 12 waves/CU. Measured 44us (best variant).
__global__ __launch_bounds__(256) void k_av_mfma(const u16* __restrict__ Ab,
                                                 const u16* __restrict__ Vtb,
                                                 const u16* __restrict__ PNb,
                                                 const u16* __restrict__ Wtb,
                                                 const float* __restrict__ bg,
                                                 u16* __restrict__ GOb) {
  __shared__ u16 As[64 * 264];
  __shared__ u16 Ts[4][32 * 72];
  const int t = threadIdx.x;
  const int wid = t >> 6, lane = t & 63;
  const int mrow = lane & 15, quad = lane >> 4;
  const int h = blockIdx.z;
  const int i0 = blockIdx.y * 64;
  const u16* ag = Ab + (size_t)h * 65536 + (size_t)i0 * 256;
#pragma unroll
  for (int u = 0; u < 8; ++u) {
    int id = u * 256 + t;
    int rr = id >> 5, c8 = (id & 31) * 8;
    *(short8*)&As[rr * 264 + c8] = *(const short8*)(ag + (size_t)rr * 256 + c8);
  }
  __syncthreads();
  const u16* vg = Vtb + (size_t)h * 2097152;
  const u16* Wg3 = Wtb + (size_t)3 * 32768;
  // hoisted gate B-frags (Wg cols e = h*32 + eh*16 + mrow) + bg
  short8 bfrg[2][4];
  float bgv2[2];
#pragma unroll
  for (int eh = 0; eh < 2; ++eh) {
#pragma unroll
    for (int kk = 0; kk < 4; ++kk)
      bfrg[eh][kk] =
          *(const short8*)(Wg3 + (size_t)(h * 32 + eh * 16 + mrow) * 128 + kk * 32 + quad * 8);
    bgv2[eh] = bg[h * 32 + eh * 16 + mrow];
  }
  u16* tw = &Ts[wid][0];
  const int c = lane & 7, lr = lane >> 3;
  const int nbase = blockIdx.x * 256 + wid * 64;  // 64 n-values per wave
  const int kslot0 = nbase >> 5;
  // ---- gate tiles for this wave's 2 kslots ----
  short4v gbf[2][4][2];
  {
    float4v gacc[2][4][2];
#pragma unroll
    for (int ks = 0; ks < 2; ++ks)
#pragma unroll
      for (int mt = 0; mt < 4; ++mt)
#pragma unroll
        for (int eh = 0; eh < 2; ++eh) gacc[ks][mt][eh] = (float4v){0.f, 0.f, 0.f, 0.f};
#pragma unroll
    for (int ks = 0; ks < 2; ++ks) {
#pragma unroll
      for (int mt = 0; mt < 4; ++mt) {
        const int p0 = (kslot0 + ks) * 256 + i0 + mt * 16;
        short8 afg[4];
#pragma unroll
        for (int kk = 0; kk < 4; ++kk)
          afg[kk] = *(const short8*)(PNb + (size_t)(p0 + mrow) * 128 + kk * 32 + quad * 8);
#pragma unroll
        for (int kk = 0; kk < 4; ++kk)
#pragma unroll
          for (int eh = 0; eh < 2; ++eh)
            gacc[ks][mt][eh] = __builtin_amdgcn_mfma_f32_16x16x32_bf16(afg[kk], bfrg[eh][kk],
                                                                       gacc[ks][mt][eh], 0, 0, 0);
      }
    }
#pragma unroll
    for (int ks = 0; ks < 2; ++ks)
#pragma unroll
      for (int mt = 0; mt < 4; ++mt)
#pragma unroll
        for (int eh = 0; eh < 2; ++eh) {
          short4v pk;
#pragma unroll
          for (int reg = 0; reg < 4; ++reg) {
            float ex = __expf(-(gacc[ks][mt][eh][reg] + bgv2[eh]));
            pk[reg] = (short)f2bf(__builtin_amdgcn_rcpf(1.0f + ex));
          }
          gbf[ks][mt][eh] = pk;
        }
  }
  // ---- AV MFMA (A-frags from shared As) ----
  float4v acc[4][4];
#pragma unroll
  for (int a = 0; a < 4; ++a)
#pragma unroll
    for (int bq = 0; bq < 4; ++bq) acc[a][bq] = (float4v){0.f, 0.f, 0.f, 0.f};
#pragma unroll
  for (int kk = 0; kk < 8; ++kk) {
    short8 afr[4], bfr[4];
#pragma unroll
    for (int mt = 0; mt < 4; ++mt)
      afr[mt] = *(const short8*)&As[(mt * 16 + mrow) * 264 + kk * 32 + quad * 8];
#pragma unroll
    for (int nn = 0; nn < 4; ++nn)
      bfr[nn] = *(const short8*)(vg + (size_t)(nbase + nn * 16 + mrow) * 256 + kk * 32 + quad * 8);
#pragma unroll
    for (int mt = 0; mt < 4; ++mt)
#pragma unroll
      for (int nn = 0; nn < 4; ++nn)
        acc[mt][nn] = __builtin_amdgcn_mfma_f32_16x16x32_bf16(afr[mt], bfr[nn], acc[mt][nn], 0, 0, 0);
  }
  // ---- gate + LDS transpose + coalesced store, two 32-row halves ----
#pragma unroll
  for (int mth = 0; mth < 2; ++mth) {
#pragma unroll
    for (int mt2 = 0; mt2 < 2; ++mt2) {
      const int mt = mth * 2 + mt2;
#pragma unroll
      for (int nn = 0; nn < 4; ++nn) {
        short4v g4 = gbf[nn >> 1][mt][nn & 1];
        const int il0 = mt2 * 16 + quad * 4;
        const int nl = nn * 16 + mrow;
#pragma unroll
        for (int reg = 0; reg < 4; ++reg) {
          float gv = bf2f((u16)g4[reg]);
          tw[(il0 + reg) * 72 + nl] = f2bf(acc[mt][nn][reg] * gv);
        }
      }
    }
    asm volatile("s_waitcnt lgkmcnt(0)" ::: "memory");
#pragma unroll
    for (int y = 0; y < 4; ++y) {
      const int ill = y * 8 + lr;
      short8 val = *(const short8*)(tw + ill * 72 + c * 8);
      const int i = i0 + mth * 32 + ill;
      const int kslot = kslot0 + (c >> 2);
      size_t idx = ((size_t)i * 256 + kslot) * 256 + h * 32 + (c & 3) * 8;
      *(short8*)(GOb + idx) = val;
    }
    if (mth == 0) asm volatile("s_waitcnt lgkmcnt(0)" ::: "memory");
  }
}

// ---------------- K9: output proj (MFMA) + bias + transpose + mask ----------
__global__ __launch_bounds__(256) void k_out_mfma(const u16* __restrict__ GOb,
                                                  const u16* __restrict__ Wotb,
                                                  const float* __restrict__ bo,
                                                  const int* __restrict__ mask,
                                                  float* __restrict__ out) {
  const int wid = threadIdx.x >> 6, lane = threadIdx.x & 63;
  const int mrow = lane & 15, quad = lane >> 4;
  const int m0 = blockIdx.x * 128 + wid * 32;
  short8 afr[2][8];
#pragma unroll
  for (int mt = 0; mt < 2; ++mt) {
    const u16* ar = GOb + (size_t)(m0 + mt * 16 + mrow) * 256 + quad * 8;
#pragma unroll
    for (int kk = 0; kk < 8; ++kk) afr[mt][kk] = *(const short8*)(ar + kk * 32);
  }
  for (int nt = 0; nt < 8; ++nt) {
    float4v acc[2];
    acc[0] = (float4v){0.f, 0.f, 0.f, 0.f};
    acc[1] = (float4v){0.f, 0.f, 0.f, 0.f};
    const u16* br = Wotb + (size_t)(nt * 16 + mrow) * 256 + quad * 8;
#pragma unroll
    for (int kk = 0; kk < 8; ++kk) {
      short8 bfr = *(const short8*)(br + kk * 32);
#pragma unroll
      for (int mt = 0; mt < 2; ++mt)
        acc[mt] = __builtin_amdgcn_mfma_f32_16x16x32_bf16(afr[mt][kk], bfr, acc[mt], 0, 0, 0);
    }
    const int c = nt * 16 + mrow;
    float bov = bo[c];
#pragma unroll
    for (int mt = 0; mt < 2; ++mt) {
#pragma unroll
      for (int reg = 0; reg < 4; ++reg) {
        int m = m0 + mt * 16 + quad * 4 + reg;  // = i*256 + k
        int i = m >> 8, kq = m & 255;
        float v = acc[mt][reg] + bov;
        bool z = (mask[i] == 0) || (mask[kq] == 0);
        __builtin_nontemporal_store(z ? 0.f : v, &out[((size_t)kq * 256 + i) * 128 + c]);
      }
    }
  }
}

extern "C" void kernel_launch(void* const* d_in, const int* in_sizes, int n_in,
                              void* d_out, int out_size, void* d_ws, size_t ws_size,
                              hipStream_t stream) {
  const float* pair = (const float*)d_in[0];
  const float* bias = (const float*)d_in[1];
  const int* mask = (const int*)d_in[2];
  const float* g_pair = (const float*)d_in[3];
  const float* b_pair = (const float*)d_in[4];
  const float* g_bias = (const float*)d_in[5];
  const float* b_bias = (const float*)d_in[6];
  const float* Wq = (const float*)d_in[7];
  const float* Wk = (const float*)d_in[8];
  const float* Wv = (const float*)d_in[9];
  const float* Wb = (const float*)d_in[10];
  const float* Wg = (const float*)d_in[11];
  const float* bg = (const float*)d_in[12];
  const float* Wo = (const float*)d_in[13];
  const float* bo = (const float*)d_in[14];
  float* out = (float*)d_out;
  char* ws = (char*)d_ws;

  u16* PNb = (u16*)(ws + 0);
  u16* Qr4 = (u16*)(ws + 16777216);
  u16* Kr4 = (u16*)(ws + 50331648);
  u16* Vtb = (u16*)(ws + 83886080);
  u16* GOb = (u16*)(ws + 150994944);
  float* Bp = (float*)(ws + 184549376);
  u16* Ab = (u16*)(ws + 186646528);
  u16* Wtb = (u16*)(ws + 187695104);
  u16* Wotb = (u16*)(ws + 187957248);
  float* Lg2 = (float*)(ws + 188022784);

  k_pre<<<2688, 256, 0, stream>>>(pair, g_pair, b_pair, PNb, bias, g_bias, b_bias, Wb, Bp,
                                  Wq, Wk, Wv, Wg, Wo, Wtb, Wotb);
  k_proj_qkg<<<dim3(128, 4, 2), 256, 0, stream>>>(PNb, Wtb, Qr4, Kr4);
  k_projv<<<dim3(256, 4), 256, 0, stream>>>(PNb, Wtb, Vtb);
  k_logits_mfma<<<dim3(4, 8, 8), 256, 0, stream>>>(Qr4, Kr4, Lg2);
  k_softmax<<<dim3(64, 8), 256, 0, stream>>>(Bp, Lg2, mask, Ab);
  k_av_mfma<<<dim3(32, 4, 8), 256, 0, stream>>>(Ab, Vtb, PNb, Wtb, bg, GOb);
  k_out_mfma<<<512, 256, 0, stream>>>(GOb, Wotb, bo, mask, out);
}